// Round 1
// baseline (3841.231 us; speedup 1.0000x reference)
//
#include <hip/hip_runtime.h>
#include <math.h>

#define N_NODES 200000
#define T_TREES 2000
#define S_NODES 100
#define F_DIM 256
#define H_DIM 256
#define G_DIM 768   // 3*H

// ---------------------------------------------------------------------------
// Build parent[] and cnt[] from the (L,M[,C]) arrays WITHOUT knowing L or M:
// scan flat positions p; each position owns C child slots. Padding: node==N,
// child==N+1.
// ---------------------------------------------------------------------------
__global__ void k_build(const int* __restrict__ layer_nodes,
                        const int* __restrict__ child_idx,
                        const int* __restrict__ child_cnt,
                        int* __restrict__ parent,
                        int* __restrict__ cnt,
                        int LM, int C) {
    for (int p = blockIdx.x * blockDim.x + threadIdx.x; p < LM;
         p += gridDim.x * blockDim.x) {
        int node = layer_nodes[p];
        if (node < N_NODES) {
            cnt[node] = child_cnt[p];
            const int* ch = child_idx + (size_t)p * C;
            for (int c = 0; c < C; ++c) {
                int k = ch[c];
                if (k < N_NODES) parent[k] = node;
            }
        }
    }
}

// Transpose weights into B-layout: wt[k][g] = w[g][k]  (k < 256, g < 768)
__global__ void k_transpose(const float* __restrict__ w_ih,
                            const float* __restrict__ w_hh,
                            float* __restrict__ wti,
                            float* __restrict__ wth) {
    int idx = blockIdx.x * blockDim.x + threadIdx.x;  // over 768*256
    if (idx >= G_DIM * F_DIM) return;
    int g = idx % G_DIM;
    int k = idx / G_DIM;
    wti[idx] = w_ih[(size_t)g * F_DIM + k];
    wth[idx] = w_hh[(size_t)g * H_DIM + k];
}

// ---------------------------------------------------------------------------
// Fused double GEMM for step j:
//   gates_i[t][g] = sum_k x[t*100+j][k]    * w_ih[g][k]            + b_ih[g]
//   gates_h[t][g] = sum_k hsum[t*100+j][k] * w_hh[g][k] * invden   + b_hh[g]
// M=2000 (trees), N=768 (gates), K=256. 64x64 tiles, 256 threads, 4x4/thread.
// ---------------------------------------------------------------------------
__global__ __launch_bounds__(256) void k_gates(
    const float* __restrict__ x,
    const float* __restrict__ hsum,
    const float* __restrict__ wti,
    const float* __restrict__ wth,
    const float* __restrict__ b_ih,
    const float* __restrict__ b_hh,
    const int* __restrict__ cnt,
    float* __restrict__ gi,
    float* __restrict__ gh,
    int j) {
    __shared__ float as1[16][64];
    __shared__ float as2[16][64];
    __shared__ float bs1[16][64];
    __shared__ float bs2[16][64];

    const int tid = threadIdx.x;
    const int bm = blockIdx.x;   // 0..31 (tree tiles)
    const int bn = blockIdx.y;   // 0..11 (gate tiles)

    const int tn = tid & 15;
    const int tm = tid >> 4;
    const int tm4 = tm << 2;
    const int tn4 = tn << 2;

    // A-load indices
    const int lm  = tid & 63;          // row in tile
    const int lk4 = (tid >> 6) << 2;   // kk offset 0/4/8/12
    int trow = bm * 64 + lm;
    if (trow > T_TREES - 1) trow = T_TREES - 1;
    const float* xrow = x    + (size_t)(trow * S_NODES + j) * F_DIM;
    const float* hrow = hsum + (size_t)(trow * S_NODES + j) * H_DIM;

    // B-load indices
    const int kw  = tid >> 4;          // 0..15
    const int nw4 = (tid & 15) << 2;   // 0..60
    const int ncol = bn * 64 + nw4;

    float acc1[4][4] = {};
    float acc2[4][4] = {};

    for (int kc = 0; kc < 256; kc += 16) {
        float4 a1 = *(const float4*)(xrow + kc + lk4);
        float4 a2 = *(const float4*)(hrow + kc + lk4);
        float4 b1 = *(const float4*)(wti + (size_t)(kc + kw) * G_DIM + ncol);
        float4 b2 = *(const float4*)(wth + (size_t)(kc + kw) * G_DIM + ncol);

        __syncthreads();
        as1[lk4 + 0][lm] = a1.x; as1[lk4 + 1][lm] = a1.y;
        as1[lk4 + 2][lm] = a1.z; as1[lk4 + 3][lm] = a1.w;
        as2[lk4 + 0][lm] = a2.x; as2[lk4 + 1][lm] = a2.y;
        as2[lk4 + 2][lm] = a2.z; as2[lk4 + 3][lm] = a2.w;
        *(float4*)&bs1[kw][nw4] = b1;
        *(float4*)&bs2[kw][nw4] = b2;
        __syncthreads();

#pragma unroll
        for (int kk = 0; kk < 16; ++kk) {
            float4 av1 = *(const float4*)&as1[kk][tm4];
            float4 av2 = *(const float4*)&as2[kk][tm4];
            float4 bv1 = *(const float4*)&bs1[kk][tn4];
            float4 bv2 = *(const float4*)&bs2[kk][tn4];
            float A1[4] = {av1.x, av1.y, av1.z, av1.w};
            float A2[4] = {av2.x, av2.y, av2.z, av2.w};
            float B1[4] = {bv1.x, bv1.y, bv1.z, bv1.w};
            float B2[4] = {bv2.x, bv2.y, bv2.z, bv2.w};
#pragma unroll
            for (int mi = 0; mi < 4; ++mi)
#pragma unroll
                for (int ni = 0; ni < 4; ++ni) {
                    acc1[mi][ni] = fmaf(A1[mi], B1[ni], acc1[mi][ni]);
                    acc2[mi][ni] = fmaf(A2[mi], B2[ni], acc2[mi][ni]);
                }
        }
    }

    const int t0 = bm * 64 + tm4;
    const int n0 = bn * 64 + tn4;
#pragma unroll
    for (int mi = 0; mi < 4; ++mi) {
        int t = t0 + mi;
        if (t >= T_TREES) break;
        int node = t * S_NODES + j;
        int c = cnt[node];
        float invden = 1.0f / (float)(c > 0 ? c : 1);
        float* girow = gi + (size_t)t * G_DIM + n0;
        float* ghrow = gh + (size_t)t * G_DIM + n0;
#pragma unroll
        for (int ni = 0; ni < 4; ++ni) {
            girow[ni] = acc1[mi][ni] + b_ih[n0 + ni];
            ghrow[ni] = acc2[mi][ni] * invden + b_hh[n0 + ni];
        }
    }
}

// ---------------------------------------------------------------------------
// GRU combine + scatter-to-parent for step j. grid=(2000), block=(256).
// ---------------------------------------------------------------------------
__global__ __launch_bounds__(256) void k_combine(
    const float* __restrict__ gi,
    const float* __restrict__ gh,
    float* __restrict__ hsum,
    const int* __restrict__ cnt,
    const int* __restrict__ parent,
    float* __restrict__ out,
    int j) {
    const int t = blockIdx.x;
    const int k = threadIdx.x;
    const int node = t * S_NODES + j;

    int c = cnt[node];
    float invden = 1.0f / (float)(c > 0 ? c : 1);
    float hp = hsum[(size_t)node * H_DIM + k] * invden;

    const float* girow = gi + (size_t)t * G_DIM;
    const float* ghrow = gh + (size_t)t * G_DIM;

    float xr = girow[k]       + ghrow[k];
    float xz = girow[256 + k] + ghrow[256 + k];
    float hgn = ghrow[512 + k];
    float xn = girow[512 + k];

    float r = 1.0f / (1.0f + expf(-xr));
    float z = 1.0f / (1.0f + expf(-xz));
    float n = tanhf(xn + r * hgn);
    float h = (1.0f - z) * n + z * hp;

    if (j == 0) {
        out[(size_t)t * H_DIM + k] = h;
    } else {
        int p = parent[node];
        hsum[(size_t)p * H_DIM + k] += h;
    }
}

// ---------------------------------------------------------------------------
extern "C" void kernel_launch(void* const* d_in, const int* in_sizes, int n_in,
                              void* d_out, int out_size, void* d_ws, size_t ws_size,
                              hipStream_t stream) {
    const float* inputs = (const float*)d_in[0];
    const float* w_ih   = (const float*)d_in[1];
    const float* w_hh   = (const float*)d_in[2];
    const float* b_ih   = (const float*)d_in[3];
    const float* b_hh   = (const float*)d_in[4];
    const int* layer_nodes = (const int*)d_in[5];
    const int* child_idx   = (const int*)d_in[6];
    const int* child_cnt   = (const int*)d_in[7];
    // root_idx (d_in[8]) not needed: roots are t*S_NODES, in tree order.

    const int LM = in_sizes[5];
    const int C  = in_sizes[6] / in_sizes[5];

    char* w = (char*)d_ws;
    size_t o = 0;
    auto alloc = [&](size_t bytes) {
        void* p = w + o;
        o += (bytes + 255) & ~(size_t)255;
        return p;
    };
    int*   parent = (int*)alloc((size_t)N_NODES * 4);
    int*   cnt    = (int*)alloc((size_t)N_NODES * 4);
    float* wti    = (float*)alloc((size_t)F_DIM * G_DIM * 4);
    float* wth    = (float*)alloc((size_t)H_DIM * G_DIM * 4);
    float* hsum   = (float*)alloc((size_t)N_NODES * H_DIM * 4);
    float* gi     = (float*)alloc((size_t)T_TREES * G_DIM * 4);
    float* gh     = (float*)alloc((size_t)T_TREES * G_DIM * 4);
    (void)ws_size;

    hipMemsetAsync(parent, 0xFF, (size_t)N_NODES * 4, stream);      // parent = -1
    hipMemsetAsync(cnt, 0, (size_t)N_NODES * 4, stream);
    hipMemsetAsync(hsum, 0, (size_t)N_NODES * H_DIM * 4, stream);

    k_build<<<256, 256, 0, stream>>>(layer_nodes, child_idx, child_cnt,
                                     parent, cnt, LM, C);
    k_transpose<<<(G_DIM * F_DIM + 255) / 256, 256, 0, stream>>>(w_ih, w_hh, wti, wth);

    for (int j = S_NODES - 1; j >= 0; --j) {
        dim3 grid((T_TREES + 63) / 64, G_DIM / 64);
        k_gates<<<grid, 256, 0, stream>>>(inputs, hsum, wti, wth, b_ih, b_hh,
                                          cnt, gi, gh, j);
        k_combine<<<T_TREES, 256, 0, stream>>>(gi, gh, hsum, cnt, parent,
                                               (float*)d_out, j);
    }
}

// Round 2
// 2907.186 us; speedup vs baseline: 1.3213x; 1.3213x over previous
//
#include <hip/hip_runtime.h>
#include <math.h>

#define N_NODES 200000
#define T_TREES 2000
#define S_NODES 100
#define F_DIM 256
#define H_DIM 256
#define G_DIM 768   // 3*H

typedef __attribute__((ext_vector_type(8))) short short8b;   // 8 bf16 = 4 VGPR
typedef __attribute__((ext_vector_type(4))) float f32x4;

static __device__ __forceinline__ unsigned short f2bf(float x) {
    unsigned u = __float_as_uint(x);
    u += 0x7FFFu + ((u >> 16) & 1u);   // round-to-nearest-even
    return (unsigned short)(u >> 16);
}
static __device__ __forceinline__ float bf2f(unsigned short u) {
    return __uint_as_float(((unsigned)u) << 16);
}

// ---------------------------------------------------------------------------
__global__ void k_zero(float4* __restrict__ p, int n4) {
    float4 z = make_float4(0.f, 0.f, 0.f, 0.f);
    for (int i = blockIdx.x * blockDim.x + threadIdx.x; i < n4;
         i += gridDim.x * blockDim.x)
        p[i] = z;
}

// Build parent[] and cnt[] from the flat (L,M[,C]) arrays (layout-free scan).
__global__ void k_build(const int* __restrict__ layer_nodes,
                        const int* __restrict__ child_idx,
                        const int* __restrict__ child_cnt,
                        int* __restrict__ parent,
                        int* __restrict__ cnt,
                        int LM, int C) {
    for (int p = blockIdx.x * blockDim.x + threadIdx.x; p < LM;
         p += gridDim.x * blockDim.x) {
        int node = layer_nodes[p];
        if (node < N_NODES) {
            cnt[node] = child_cnt[p];
            const int* ch = child_idx + (size_t)p * C;
            for (int c = 0; c < C; ++c) {
                int k = ch[c];
                if (k < N_NODES) parent[k] = node;
            }
        }
    }
}

// Convert both weight matrices to bf16 (same row-major [g][k] layout).
__global__ void k_convw(const float* __restrict__ wi, const float* __restrict__ wh,
                        unsigned short* __restrict__ wib, unsigned short* __restrict__ whb) {
    int i = blockIdx.x * blockDim.x + threadIdx.x;
    if (i < G_DIM * F_DIM) {
        wib[i] = f2bf(wi[i]);
        whb[i] = f2bf(wh[i]);
    }
}

// ---------------------------------------------------------------------------
// Big one-shot GEMM: gi_all[m][g] = sum_k x[m][k] * w_ih[g][k]  (bf16 out)
// M=200000, N=768, K=256. Block=256thr=4 waves; wave tile 64m x 64n, A in regs.
// ---------------------------------------------------------------------------
__global__ __launch_bounds__(256) void k_gemm_x(
    const float* __restrict__ x,
    const unsigned short* __restrict__ wib,
    unsigned short* __restrict__ gi_all) {
    const int tid = threadIdx.x;
    const int wv = tid >> 6, lane = tid & 63;
    const int lr = lane & 15, kg = lane >> 4;
    const long m0 = (long)blockIdx.x * 256 + wv * 64;

    short8b A[4][8];
#pragma unroll
    for (int ms = 0; ms < 4; ++ms) {
        long r = m0 + ms * 16 + lr;
        if (r > N_NODES - 1) r = N_NODES - 1;
        const float* xp = x + r * F_DIM + kg * 8;
#pragma unroll
        for (int ks = 0; ks < 8; ++ks) {
            float4 u = *(const float4*)(xp + ks * 32);
            float4 v = *(const float4*)(xp + ks * 32 + 4);
            short8b t;
            t[0] = f2bf(u.x); t[1] = f2bf(u.y); t[2] = f2bf(u.z); t[3] = f2bf(u.w);
            t[4] = f2bf(v.x); t[5] = f2bf(v.y); t[6] = f2bf(v.z); t[7] = f2bf(v.w);
            A[ms][ks] = t;
        }
    }

    const f32x4 zf = {0.f, 0.f, 0.f, 0.f};
    for (int nt = 0; nt < 12; ++nt) {
        f32x4 acc[4][4];
#pragma unroll
        for (int ms = 0; ms < 4; ++ms)
#pragma unroll
            for (int ns = 0; ns < 4; ++ns) acc[ms][ns] = zf;

#pragma unroll
        for (int ks = 0; ks < 8; ++ks) {
            short8b B[4];
#pragma unroll
            for (int ns = 0; ns < 4; ++ns)
                B[ns] = *(const short8b*)(wib + (size_t)(nt * 64 + ns * 16 + lr) * F_DIM
                                          + ks * 32 + kg * 8);
#pragma unroll
            for (int ms = 0; ms < 4; ++ms)
#pragma unroll
                for (int ns = 0; ns < 4; ++ns)
                    acc[ms][ns] = __builtin_amdgcn_mfma_f32_16x16x32_bf16(
                        A[ms][ks], B[ns], acc[ms][ns], 0, 0, 0);
        }

#pragma unroll
        for (int ms = 0; ms < 4; ++ms)
#pragma unroll
            for (int ns = 0; ns < 4; ++ns) {
                long mb = m0 + ms * 16 + kg * 4;
                int g = nt * 64 + ns * 16 + lr;
#pragma unroll
                for (int i = 0; i < 4; ++i) {
                    long m = mb + i;
                    if (m < N_NODES)
                        gi_all[m * G_DIM + g] = f2bf(acc[ms][ns][i]);
                }
            }
    }
}

// ---------------------------------------------------------------------------
// Per-step recurrent GEMM: gh[t][g] = sum_k (hsum[t*100+j][k]*invden) * w_hh[g][k]
// M=2048(pad), N=768, K=256. grid=(8,12); block=4 waves x (64m x 64n), nt=blockIdx.y
// ---------------------------------------------------------------------------
__global__ __launch_bounds__(256) void k_gemm_h(
    const float* __restrict__ hsum,
    const unsigned short* __restrict__ whb,
    const int* __restrict__ cnt,
    float* __restrict__ gh, int j) {
    const int tid = threadIdx.x;
    const int wv = tid >> 6, lane = tid & 63;
    const int lr = lane & 15, kg = lane >> 4;
    const int m0 = blockIdx.x * 256 + wv * 64;
    const int nt = blockIdx.y;

    short8b A[4][8];
#pragma unroll
    for (int ms = 0; ms < 4; ++ms) {
        int t = m0 + ms * 16 + lr;
        if (t > T_TREES - 1) t = T_TREES - 1;
        int node = t * S_NODES + j;
        int c = cnt[node];
        float inv = 1.0f / (float)(c > 0 ? c : 1);
        const float* hp = hsum + (size_t)node * H_DIM + kg * 8;
#pragma unroll
        for (int ks = 0; ks < 8; ++ks) {
            float4 u = *(const float4*)(hp + ks * 32);
            float4 v = *(const float4*)(hp + ks * 32 + 4);
            short8b t8;
            t8[0] = f2bf(u.x * inv); t8[1] = f2bf(u.y * inv);
            t8[2] = f2bf(u.z * inv); t8[3] = f2bf(u.w * inv);
            t8[4] = f2bf(v.x * inv); t8[5] = f2bf(v.y * inv);
            t8[6] = f2bf(v.z * inv); t8[7] = f2bf(v.w * inv);
            A[ms][ks] = t8;
        }
    }

    const f32x4 zf = {0.f, 0.f, 0.f, 0.f};
    f32x4 acc[4][4];
#pragma unroll
    for (int ms = 0; ms < 4; ++ms)
#pragma unroll
        for (int ns = 0; ns < 4; ++ns) acc[ms][ns] = zf;

#pragma unroll
    for (int ks = 0; ks < 8; ++ks) {
        short8b B[4];
#pragma unroll
        for (int ns = 0; ns < 4; ++ns)
            B[ns] = *(const short8b*)(whb + (size_t)(nt * 64 + ns * 16 + lr) * H_DIM
                                      + ks * 32 + kg * 8);
#pragma unroll
        for (int ms = 0; ms < 4; ++ms)
#pragma unroll
            for (int ns = 0; ns < 4; ++ns)
                acc[ms][ns] = __builtin_amdgcn_mfma_f32_16x16x32_bf16(
                    A[ms][ks], B[ns], acc[ms][ns], 0, 0, 0);
    }

#pragma unroll
    for (int ms = 0; ms < 4; ++ms)
#pragma unroll
        for (int ns = 0; ns < 4; ++ns) {
            int mb = m0 + ms * 16 + kg * 4;
            int g = nt * 64 + ns * 16 + lr;
#pragma unroll
            for (int i = 0; i < 4; ++i) {
                int t = mb + i;
                if (t < T_TREES) gh[(size_t)t * G_DIM + g] = acc[ms][ns][i];
            }
        }
}

// ---------------------------------------------------------------------------
// GRU combine + scatter-to-parent. grid=(2000), block=(256).
// ---------------------------------------------------------------------------
__global__ __launch_bounds__(256) void k_combine(
    const unsigned short* __restrict__ gi_all,
    const float* __restrict__ gh,
    float* __restrict__ hsum,
    const int* __restrict__ cnt,
    const int* __restrict__ parent,
    const float* __restrict__ b_ih,
    const float* __restrict__ b_hh,
    float* __restrict__ out, int j) {
    const int t = blockIdx.x;
    const int k = threadIdx.x;
    const int node = t * S_NODES + j;

    int c = cnt[node];
    float inv = 1.0f / (float)(c > 0 ? c : 1);
    float hp = hsum[(size_t)node * H_DIM + k] * inv;

    const unsigned short* gi = gi_all + (size_t)node * G_DIM;
    const float* ghr = gh + (size_t)t * G_DIM;

    float xr = bf2f(gi[k])       + b_ih[k]       + ghr[k]       + b_hh[k];
    float xz = bf2f(gi[256 + k]) + b_ih[256 + k] + ghr[256 + k] + b_hh[256 + k];
    float xn = bf2f(gi[512 + k]) + b_ih[512 + k];
    float hg = ghr[512 + k] + b_hh[512 + k];

    float r = 1.0f / (1.0f + expf(-xr));
    float z = 1.0f / (1.0f + expf(-xz));
    float n = tanhf(xn + r * hg);
    float h = (1.0f - z) * n + z * hp;

    if (j == 0) {
        out[(size_t)t * H_DIM + k] = h;
    } else {
        hsum[(size_t)parent[node] * H_DIM + k] += h;
    }
}

// ---------------------------------------------------------------------------
extern "C" void kernel_launch(void* const* d_in, const int* in_sizes, int n_in,
                              void* d_out, int out_size, void* d_ws, size_t ws_size,
                              hipStream_t stream) {
    const float* inputs = (const float*)d_in[0];
    const float* w_ih   = (const float*)d_in[1];
    const float* w_hh   = (const float*)d_in[2];
    const float* b_ih   = (const float*)d_in[3];
    const float* b_hh   = (const float*)d_in[4];
    const int* layer_nodes = (const int*)d_in[5];
    const int* child_idx   = (const int*)d_in[6];
    const int* child_cnt   = (const int*)d_in[7];

    const int LM = in_sizes[5];
    const int C  = in_sizes[6] / in_sizes[5];

    char* w = (char*)d_ws;
    size_t o = 0;
    auto alloc = [&](size_t bytes) {
        void* p = w + o;
        o += (bytes + 255) & ~(size_t)255;
        return p;
    };
    int*            parent = (int*)alloc((size_t)N_NODES * 4);
    int*            cnt    = (int*)alloc((size_t)N_NODES * 4);
    unsigned short* wib    = (unsigned short*)alloc((size_t)G_DIM * F_DIM * 2);
    unsigned short* whb    = (unsigned short*)alloc((size_t)G_DIM * H_DIM * 2);
    float*          gh     = (float*)alloc((size_t)T_TREES * G_DIM * 4);
    float*          hsum   = (float*)alloc((size_t)N_NODES * H_DIM * 4);
    unsigned short* gi_all = (unsigned short*)alloc((size_t)N_NODES * G_DIM * 2);
    (void)ws_size;

    // hsum = 0 (parent/cnt are fully overwritten by k_build; no memset needed)
    k_zero<<<2048, 256, 0, stream>>>((float4*)hsum, N_NODES * H_DIM / 4);
    k_build<<<256, 256, 0, stream>>>(layer_nodes, child_idx, child_cnt,
                                     parent, cnt, LM, C);
    k_convw<<<(G_DIM * F_DIM + 255) / 256, 256, 0, stream>>>(w_ih, w_hh, wib, whb);

    // One-shot feed-forward GEMM over all nodes
    k_gemm_x<<<(N_NODES + 255) / 256, 256, 0, stream>>>(inputs, wib, gi_all);

    for (int j = S_NODES - 1; j >= 0; --j) {
        k_gemm_h<<<dim3(8, 12), 256, 0, stream>>>(hsum, whb, cnt, gh, j);
        k_combine<<<T_TREES, 256, 0, stream>>>(gi_all, gh, hsum, cnt, parent,
                                               b_ih, b_hh, (float*)d_out, j);
    }
}

// Round 3
// 1366.168 us; speedup vs baseline: 2.8117x; 2.1280x over previous
//
#include <hip/hip_runtime.h>
#include <math.h>

#define N_NODES 200000
#define T_TREES 2000
#define S_NODES 100
#define F_DIM 256
#define H_DIM 256
#define G_DIM 768   // 3*H
#define TRB 16      // trees per block in recurrence
#define NBLK (T_TREES / TRB)   // 125

typedef __attribute__((ext_vector_type(8))) short short8b;   // 8 bf16 = 4 VGPR
typedef __attribute__((ext_vector_type(4))) float f32x4;

static __device__ __forceinline__ unsigned short f2bf(float x) {
    unsigned u = __float_as_uint(x);
    u += 0x7FFFu + ((u >> 16) & 1u);   // round-to-nearest-even
    return (unsigned short)(u >> 16);
}
static __device__ __forceinline__ float bf2f(unsigned short u) {
    return __uint_as_float(((unsigned)u) << 16);
}

// ---------------------------------------------------------------------------
__global__ void k_zero(float4* __restrict__ p, int n4) {
    float4 z = make_float4(0.f, 0.f, 0.f, 0.f);
    for (int i = blockIdx.x * blockDim.x + threadIdx.x; i < n4;
         i += gridDim.x * blockDim.x)
        p[i] = z;
}

// Build parent[] and cnt[] from the flat (L,M[,C]) arrays (layout-free scan).
__global__ void k_build(const int* __restrict__ layer_nodes,
                        const int* __restrict__ child_idx,
                        const int* __restrict__ child_cnt,
                        int* __restrict__ parent,
                        int* __restrict__ cnt,
                        int LM, int C) {
    for (int p = blockIdx.x * blockDim.x + threadIdx.x; p < LM;
         p += gridDim.x * blockDim.x) {
        int node = layer_nodes[p];
        if (node < N_NODES) {
            cnt[node] = child_cnt[p];
            const int* ch = child_idx + (size_t)p * C;
            for (int c = 0; c < C; ++c) {
                int k = ch[c];
                if (k < N_NODES) parent[k] = node;
            }
        }
    }
}

// Convert both weight matrices to bf16 (row-major [g][k]).
__global__ void k_convw(const float* __restrict__ wi, const float* __restrict__ wh,
                        unsigned short* __restrict__ wib, unsigned short* __restrict__ whb) {
    int i = blockIdx.x * blockDim.x + threadIdx.x;
    if (i < G_DIM * F_DIM) {
        wib[i] = f2bf(wi[i]);
        whb[i] = f2bf(wh[i]);
    }
}

// ---------------------------------------------------------------------------
// One-shot GEMM: gi_all[m][g] = (sum_k x[m][k] * w_ih[g][k]) + b_ih[g]  (bf16)
// Swapped MFMA operands so regs hold 4 consecutive g -> 8B packed stores.
// ---------------------------------------------------------------------------
__global__ __launch_bounds__(256) void k_gemm_x(
    const float* __restrict__ x,
    const unsigned short* __restrict__ wib,
    const float* __restrict__ b_ih,
    unsigned short* __restrict__ gi_all) {
    const int tid = threadIdx.x;
    const int wv = tid >> 6, lane = tid & 63;
    const int lr = lane & 15, kg = lane >> 4;
    const long m0 = (long)blockIdx.x * 256 + wv * 64;

    short8b A[4][8];
#pragma unroll
    for (int ms = 0; ms < 4; ++ms) {
        long r = m0 + ms * 16 + lr;
        if (r > N_NODES - 1) r = N_NODES - 1;
        const float* xp = x + r * F_DIM + kg * 8;
#pragma unroll
        for (int ks = 0; ks < 8; ++ks) {
            float4 u = *(const float4*)(xp + ks * 32);
            float4 v = *(const float4*)(xp + ks * 32 + 4);
            short8b t;
            t[0] = f2bf(u.x); t[1] = f2bf(u.y); t[2] = f2bf(u.z); t[3] = f2bf(u.w);
            t[4] = f2bf(v.x); t[5] = f2bf(v.y); t[6] = f2bf(v.z); t[7] = f2bf(v.w);
            A[ms][ks] = t;
        }
    }

    const f32x4 zf = {0.f, 0.f, 0.f, 0.f};
    for (int nt = 0; nt < 12; ++nt) {
        f32x4 acc[4][4];   // [ms][ns]; regs = g-dim, lanes = m-dim (swapped)
#pragma unroll
        for (int ms = 0; ms < 4; ++ms)
#pragma unroll
            for (int ns = 0; ns < 4; ++ns) acc[ms][ns] = zf;

#pragma unroll
        for (int ks = 0; ks < 8; ++ks) {
            short8b B[4];
#pragma unroll
            for (int ns = 0; ns < 4; ++ns)
                B[ns] = *(const short8b*)(wib + (size_t)(nt * 64 + ns * 16 + lr) * F_DIM
                                          + ks * 32 + kg * 8);
#pragma unroll
            for (int ms = 0; ms < 4; ++ms)
#pragma unroll
                for (int ns = 0; ns < 4; ++ns)
                    acc[ms][ns] = __builtin_amdgcn_mfma_f32_16x16x32_bf16(
                        B[ns], A[ms][ks], acc[ms][ns], 0, 0, 0);
        }

        float4 bi[4];
#pragma unroll
        for (int ns = 0; ns < 4; ++ns)
            bi[ns] = *(const float4*)(b_ih + nt * 64 + ns * 16 + kg * 4);

#pragma unroll
        for (int ms = 0; ms < 4; ++ms) {
            long m = m0 + ms * 16 + lr;
            if (m < N_NODES) {
#pragma unroll
                for (int ns = 0; ns < 4; ++ns) {
                    int g0 = nt * 64 + ns * 16 + kg * 4;
                    ushort4 pk;
                    pk.x = f2bf(acc[ms][ns][0] + bi[ns].x);
                    pk.y = f2bf(acc[ms][ns][1] + bi[ns].y);
                    pk.z = f2bf(acc[ms][ns][2] + bi[ns].z);
                    pk.w = f2bf(acc[ms][ns][3] + bi[ns].w);
                    *(ushort4*)(gi_all + m * G_DIM + g0) = pk;
                }
            }
        }
    }
}

// ---------------------------------------------------------------------------
// Whole recurrence in ONE kernel. Block owns 16 trees; all child->parent
// scatters stay inside the block (parent idx < child idx, same tree), so no
// inter-block sync is needed. 4 waves; wave wv owns gate-cols [wv*64,wv*64+64)
// of each of the 3 gate chunks (12 n-tiles, 96 MFMA per step).
// ---------------------------------------------------------------------------
__global__ __launch_bounds__(256) void k_recur(
    float* __restrict__ hsum,
    const unsigned short* __restrict__ whb,
    const unsigned short* __restrict__ gi_all,
    const float* __restrict__ b_hh,
    const int* __restrict__ cnt,
    const int* __restrict__ parent,
    float* __restrict__ out) {
    __shared__ unsigned short Ab[TRB][264];  // scaled h_prev, bf16 (padded)
    __shared__ float Hp[TRB][260];           // scaled h_prev, fp32 (padded)
    __shared__ int Par[TRB];

    const int tid = threadIdx.x;
    const int wv = tid >> 6, lane = tid & 63;
    const int lr = lane & 15, kg = lane >> 4;
    const int cb = wv * 64;
    const int blk = blockIdx.x;

    // loop-invariant b_hh per (chunk, ns)
    float bh[3][4];
#pragma unroll
    for (int c = 0; c < 3; ++c)
#pragma unroll
        for (int ns = 0; ns < 4; ++ns)
            bh[c][ns] = b_hh[c * 256 + cb + ns * 16 + lr];

    const int srow = tid >> 4;          // staging row 0..15
    const int scol = (tid & 15) * 16;   // 16 floats per thread

    for (int j = S_NODES - 1; j >= 0; --j) {
        // ---- stage h_prev = hsum/denom for this block's 16 nodes ----
        {
            int t = blk * TRB + srow;
            int node = t * S_NODES + j;
            int c = cnt[node];
            float inv = 1.0f / (float)(c > 0 ? c : 1);
            const float* hr = hsum + (size_t)node * H_DIM + scol;
            float4 u0 = *(const float4*)(hr + 0);
            float4 u1 = *(const float4*)(hr + 4);
            float4 u2 = *(const float4*)(hr + 8);
            float4 u3 = *(const float4*)(hr + 12);
            u0.x *= inv; u0.y *= inv; u0.z *= inv; u0.w *= inv;
            u1.x *= inv; u1.y *= inv; u1.z *= inv; u1.w *= inv;
            u2.x *= inv; u2.y *= inv; u2.z *= inv; u2.w *= inv;
            u3.x *= inv; u3.y *= inv; u3.z *= inv; u3.w *= inv;
            *(float4*)&Hp[srow][scol + 0]  = u0;
            *(float4*)&Hp[srow][scol + 4]  = u1;
            *(float4*)&Hp[srow][scol + 8]  = u2;
            *(float4*)&Hp[srow][scol + 12] = u3;
            short8b p0, p1;
            p0[0] = f2bf(u0.x); p0[1] = f2bf(u0.y); p0[2] = f2bf(u0.z); p0[3] = f2bf(u0.w);
            p0[4] = f2bf(u1.x); p0[5] = f2bf(u1.y); p0[6] = f2bf(u1.z); p0[7] = f2bf(u1.w);
            p1[0] = f2bf(u2.x); p1[1] = f2bf(u2.y); p1[2] = f2bf(u2.z); p1[3] = f2bf(u2.w);
            p1[4] = f2bf(u3.x); p1[5] = f2bf(u3.y); p1[6] = f2bf(u3.z); p1[7] = f2bf(u3.w);
            *(short8b*)&Ab[srow][scol + 0] = p0;
            *(short8b*)&Ab[srow][scol + 8] = p1;
            if ((tid & 15) == 0) Par[srow] = parent[node];
        }
        __syncthreads();

        // ---- early-issue gi loads (land under the MFMA phase) ----
        unsigned short gr[4][4], gz[4][4], gn[4][4];
#pragma unroll
        for (int i = 0; i < 4; ++i) {
            int te = blk * TRB + kg * 4 + i;
            const unsigned short* gp = gi_all + (size_t)(te * S_NODES + j) * G_DIM;
#pragma unroll
            for (int ns = 0; ns < 4; ++ns) {
                int k = cb + ns * 16 + lr;
                gr[ns][i] = gp[k];
                gz[ns][i] = gp[256 + k];
                gn[ns][i] = gp[512 + k];
            }
        }

        // ---- A fragments from LDS ----
        short8b A[8];
#pragma unroll
        for (int ks = 0; ks < 8; ++ks)
            A[ks] = *(const short8b*)&Ab[lr][ks * 32 + kg * 8];

        // ---- GEMM: acc[c][ns] = h_prev @ w_hh^T (inv already applied) ----
        const f32x4 zf = {0.f, 0.f, 0.f, 0.f};
        f32x4 acc[3][4];
#pragma unroll
        for (int c = 0; c < 3; ++c)
#pragma unroll
            for (int ns = 0; ns < 4; ++ns) acc[c][ns] = zf;

#pragma unroll
        for (int ks = 0; ks < 8; ++ks) {
#pragma unroll
            for (int c = 0; c < 3; ++c)
#pragma unroll
                for (int ns = 0; ns < 4; ++ns) {
                    short8b B = *(const short8b*)(whb
                        + (size_t)(c * 256 + cb + ns * 16 + lr) * H_DIM
                        + ks * 32 + kg * 8);
                    acc[c][ns] = __builtin_amdgcn_mfma_f32_16x16x32_bf16(
                        A[ks], B, acc[c][ns], 0, 0, 0);
                }
        }

        // ---- fused GRU + scatter ----
#pragma unroll
        for (int ns = 0; ns < 4; ++ns) {
            int k = cb + ns * 16 + lr;
#pragma unroll
            for (int i = 0; i < 4; ++i) {
                int rl = kg * 4 + i;
                float gir = bf2f(gr[ns][i]);   // includes b_ih
                float giz = bf2f(gz[ns][i]);
                float gin = bf2f(gn[ns][i]);
                float xr = gir + acc[0][ns][i] + bh[0][ns];
                float xz = giz + acc[1][ns][i] + bh[1][ns];
                float r = 1.0f / (1.0f + expf(-xr));
                float z = 1.0f / (1.0f + expf(-xz));
                float n = tanhf(gin + r * (acc[2][ns][i] + bh[2][ns]));
                float hp = Hp[rl][k];
                float h = (1.0f - z) * n + z * hp;
                int t = blk * TRB + rl;
                if (j == 0) {
                    out[(size_t)t * H_DIM + k] = h;
                } else {
                    atomicAdd(&hsum[(size_t)Par[rl] * H_DIM + k], h);
                }
            }
        }
        __syncthreads();   // scatters drained before next staging
    }
}

// ---------------------------------------------------------------------------
extern "C" void kernel_launch(void* const* d_in, const int* in_sizes, int n_in,
                              void* d_out, int out_size, void* d_ws, size_t ws_size,
                              hipStream_t stream) {
    const float* inputs = (const float*)d_in[0];
    const float* w_ih   = (const float*)d_in[1];
    const float* w_hh   = (const float*)d_in[2];
    const float* b_ih   = (const float*)d_in[3];
    const float* b_hh   = (const float*)d_in[4];
    const int* layer_nodes = (const int*)d_in[5];
    const int* child_idx   = (const int*)d_in[6];
    const int* child_cnt   = (const int*)d_in[7];

    const int LM = in_sizes[5];
    const int C  = in_sizes[6] / in_sizes[5];

    char* w = (char*)d_ws;
    size_t o = 0;
    auto alloc = [&](size_t bytes) {
        void* p = w + o;
        o += (bytes + 255) & ~(size_t)255;
        return p;
    };
    int*            parent = (int*)alloc((size_t)N_NODES * 4);
    int*            cnt    = (int*)alloc((size_t)N_NODES * 4);
    unsigned short* wib    = (unsigned short*)alloc((size_t)G_DIM * F_DIM * 2);
    unsigned short* whb    = (unsigned short*)alloc((size_t)G_DIM * H_DIM * 2);
    float*          hsum   = (float*)alloc((size_t)N_NODES * H_DIM * 4);
    unsigned short* gi_all = (unsigned short*)alloc((size_t)N_NODES * G_DIM * 2);
    (void)ws_size;

    k_zero<<<2048, 256, 0, stream>>>((float4*)hsum, N_NODES * H_DIM / 4);
    k_build<<<256, 256, 0, stream>>>(layer_nodes, child_idx, child_cnt,
                                     parent, cnt, LM, C);
    k_convw<<<(G_DIM * F_DIM + 255) / 256, 256, 0, stream>>>(w_ih, w_hh, wib, whb);

    // One-shot feed-forward GEMM (b_ih folded in)
    k_gemm_x<<<(N_NODES + 255) / 256, 256, 0, stream>>>(inputs, wib, b_ih, gi_all);

    // Entire 100-step recurrence in one kernel
    k_recur<<<NBLK, 256, 0, stream>>>(hsum, whb, gi_all, b_hh, cnt, parent,
                                      (float*)d_out);
}